// Round 2
// baseline (3789.397 us; speedup 1.0000x reference)
//
#include <hip/hip_runtime.h>
#include <hip/hip_fp16.h>
#include <cstdint>

#define BATCH 256
#define SEQ   2048
#define IN_DIM 4
#define HID   256
#define G4    1024   // 4*HID

// ---------- helpers ----------

typedef _Float16 h2_t __attribute__((ext_vector_type(2)));

union U32H2 { uint32_t u; h2_t h; __half2 hh; };

__device__ __forceinline__ float fdot2(uint32_t w, uint32_t h, float acc) {
#if __has_builtin(__builtin_amdgcn_fdot2)
    U32H2 a; a.u = w; U32H2 b; b.u = h;
    return __builtin_amdgcn_fdot2(a.h, b.h, acc, false);
#else
    U32H2 a; a.u = w; U32H2 b; b.u = h;
    float2 fa = __half22float2(a.hh), fb = __half22float2(b.hh);
    return acc + fa.x * fb.x + fa.y * fb.y;
#endif
}

__device__ __forceinline__ uint32_t pack_h2(float a, float b) {
    U32H2 u; u.hh = __floats2half2_rn(a, b); return u.u;
}

__device__ __forceinline__ float sigmoidf_(float x) {
    return 1.0f / (1.0f + __expf(-x));
}
__device__ __forceinline__ float tanhf_(float x) {
    return 1.0f - 2.0f / (__expf(2.0f * x) + 1.0f);
}

// ---------- ws layout (bytes) ----------
// wreg: 92 planes x 1024 rows x 4B = 376832
// wtail: 9 uint4-planes x 1024 rows x 16B = 147456  -> ends at 524288
#define OFF_WTAIL 376832
#define OFF_BIAS  524288
#define OFF_CONVF 528384
#define OFF_KSIM  529408
#define OFF_HOUT  530432

// ---------- prep: fp16 conversion + bias fuse ----------
// Layout for 1-row-per-thread recurrence (1024 threads):
//   pair-cols [0,92):   wreg plane pc -> wreg[pc*G4 + row]   (register-resident)
//   pair-cols [92,128): wtail 9 uint4 planes: plane c covers pc 92+4c..92+4c+3
//                       wtail[(c*G4 + row)*4 + d], d = pc-92-4c
__global__ void prep_kernel(const float* __restrict__ Whh,
                            const float* __restrict__ bih,
                            const float* __restrict__ bhh,
                            uint32_t* __restrict__ wreg,
                            uint32_t* __restrict__ wtail,
                            float* __restrict__ bias) {
    int gid = blockIdx.x * blockDim.x + threadIdx.x;  // 0..131071
    int row = gid >> 7;      // 0..1023
    int pr  = gid & 127;     // pair-col 0..127
    float a = Whh[row * HID + 2 * pr];
    float b = Whh[row * HID + 2 * pr + 1];
    uint32_t p = pack_h2(a, b);
    if (pr < 92) {
        wreg[pr * G4 + row] = p;
    } else {
        int q = pr - 92;            // 0..35
        int c = q >> 2, d = q & 3;  // chunk 0..8, dword 0..3
        wtail[(c * G4 + row) * 4 + d] = p;
    }
    if (gid < G4) bias[gid] = bih[gid] + bhh[gid];
}

// ---------- features: conv mean + RBF kernel sim ----------
__global__ void feat_kernel(const float* __restrict__ x,
                            const float* __restrict__ conv_w,
                            const float* __restrict__ conv_b,
                            float* __restrict__ convf,
                            float* __restrict__ ksim) {
    int b = blockIdx.x, t = threadIdx.x;  // 256 threads
    const float4* xb = (const float4*)(x + (size_t)b * SEQ * IN_DIM);
    float cw0 = conv_w[0], cw1 = conv_w[1], cw2 = conv_w[2], cw3 = conv_w[3];
    float cb = conv_b[0];
    float s_sig = 0.f, s_sq = 0.f;
#pragma unroll
    for (int k = 0; k < 8; ++k) {
        int s = t + k * 256;
        float4 v = xb[s];
        float d = v.x * cw0 + v.y * cw1 + v.z * cw2 + v.w * cw3 + cb;
        s_sig += sigmoidf_(d);
        s_sq  += v.x * v.x + v.y * v.y + v.z * v.z + v.w * v.w;
    }
    __shared__ float sA[256], sB[256];
    sA[t] = s_sig; sB[t] = s_sq;
    __syncthreads();
    for (int off = 128; off > 0; off >>= 1) {
        if (t < off) { sA[t] += sA[t + off]; sB[t] += sB[t + off]; }
        __syncthreads();
    }
    if (t == 0) {
        convf[b] = sA[0] * (1.0f / 2048.0f);
        ksim[b]  = __expf(-sB[0]);
    }
}

// ---------- LSTM recurrence: 1 sample per block ----------
// 1024 threads = 16 waves = 4 waves/SIMD. Thread t owns gate-row r = t:
//   role = t>>8 (0:i 1:f 2:g 3:o), u = t&255  -> wave-uniform roles.
// Per thread: 92 register pair-cols (92 VGPR) + 9 uint4 LDS tail chunks
// (pair-cols 92..127). All threads read the full h (32 uniform-address
// b128 broadcasts). Gate exchange via pi/pg/po (contiguous f32, conflict-
// free); f-threads own c/h. 2 barriers/step.
// VGPR budget: 1024 thr -> 16 waves -> 4/EU mandatory -> <=128 VGPR.
// 92 weights + ~30 live temps ~ 122: fits without AGPR bounce (the R0/R1
// 2-rows/thread variants pinned 192 dwords against a 124-128 VGPR alloc).
#define TAIL_DW (9 * 1024 * 4)   // 36864 dwords = 147456 B

__global__ __launch_bounds__(1024, 4)
void recur_kernel(const float* __restrict__ x,
                  const float* __restrict__ Wih,
                  const uint32_t* __restrict__ wreg,
                  const uint32_t* __restrict__ wtail,
                  const float* __restrict__ bias,
                  float* __restrict__ h_out) {
    extern __shared__ uint32_t smem[];
    uint32_t* tail  = smem;                 // 36864 dwords
    uint32_t* hbuf0 = smem + TAIL_DW;       // 128 dwords (256 fp16)
    uint32_t* hbuf1 = hbuf0 + 128;          // 128 dwords
    float*    pi    = (float*)(hbuf1 + 128);// 256 f32
    float*    pg    = pi + 256;
    float*    po    = pg + 256;

    const int b = blockIdx.x;
    const int t = threadIdx.x;
    const int role = t >> 8;    // wave-uniform
    const int u = t & 255;

    // stage w-tail into LDS (coalesced, layout identical to global)
    {
        const uint4* src = (const uint4*)wtail;
        uint4* dst = (uint4*)tail;
#pragma unroll
        for (int i = 0; i < 9; ++i) dst[t + i * 1024] = src[t + i * 1024];
    }
    if (t < 128) hbuf0[t] = 0u;  // h = 0 (fp16 zeros)

    // register-resident weights: pair-cols 0..91 of row t
    uint32_t w[92];
#pragma unroll
    for (int k = 0; k < 92; ++k) w[k] = wreg[k * G4 + t];
    // opaque no-op: pin values in VGPRs, forbid rematerialized reloads
#pragma unroll
    for (int k = 0; k < 92; ++k) asm volatile("" : "+v"(w[k]));

    const float4 wv = ((const float4*)Wih)[t];
    const float bs = bias[t];

    float c_state = 0.f;
    float h_last = 0.f;
    const float4* xb = (const float4*)(x + (size_t)b * SEQ * IN_DIM);
    const uint4* tq = (const uint4*)tail + t;   // + c*G4 per chunk

    __syncthreads();

    uint32_t* hr = hbuf0;
    uint32_t* hw = hbuf1;

    for (int s = 0; s < SEQ; ++s) {
        const float4 xt = xb[s];    // block-uniform address -> scalarized
        float a0 = bs + xt.x * wv.x + xt.y * wv.y + xt.z * wv.z + xt.w * wv.w;
        float a1 = 0.f, a2 = 0.f, a3 = 0.f;   // 4 chains: hide dot2 latency

        const uint4* hr4 = (const uint4*)hr;

        // pair-cols 0..91 from registers (23 h-chunks)
#pragma unroll
        for (int c = 0; c < 23; ++c) {
            const uint4 h4 = hr4[c];
            a0 = fdot2(w[4 * c + 0], h4.x, a0);
            a1 = fdot2(w[4 * c + 1], h4.y, a1);
            a2 = fdot2(w[4 * c + 2], h4.z, a2);
            a3 = fdot2(w[4 * c + 3], h4.w, a3);
        }
        // pair-cols 92..127 from LDS (9 chunks, contiguous spread b128)
#pragma unroll
        for (int c = 0; c < 9; ++c) {
            const uint4 wt = tq[c * G4];
            const uint4 h4 = hr4[23 + c];
            a0 = fdot2(wt.x, h4.x, a0);
            a1 = fdot2(wt.y, h4.y, a1);
            a2 = fdot2(wt.z, h4.z, a2);
            a3 = fdot2(wt.w, h4.w, a3);
        }
        const float z = (a0 + a1) + (a2 + a3);

        // phase 2: one nonlinearity per thread (wave-uniform branch)
        const float nl = (role == 2) ? tanhf_(z) : sigmoidf_(z);
        if (role == 0) pi[u] = nl;
        else if (role == 2) pg[u] = nl;
        else if (role == 3) po[u] = nl;
        __syncthreads();

        // phase 4: f-threads own c/h (nl == sigmoid(f) here)
        if (role == 1) {
            c_state = nl * c_state + pi[u] * pg[u];
            h_last = po[u] * tanhf_(c_state);
            ((__half*)hw)[u] = __float2half_rn(h_last);
        }
        __syncthreads();
        uint32_t* tmp = hr; hr = hw; hw = tmp;
    }

    if (role == 1) h_out[b * HID + u] = h_last;
}

// ---------- head: fc + relu + out + softmax ----------
__global__ void head_kernel(const float* __restrict__ fc_w,
                            const float* __restrict__ fc_b,
                            const float* __restrict__ out_w,
                            const float* __restrict__ out_b,
                            const float* __restrict__ convf,
                            const float* __restrict__ ksim,
                            const float* __restrict__ h_out,
                            float* __restrict__ out) {
    int b = blockIdx.x, j = threadIdx.x;  // 256 threads
    const float* hrow = h_out + b * HID;
    const float* w = fc_w + j * (HID + 2);
    float acc = fc_b[j] + w[0] * convf[b] + w[HID + 1] * ksim[b];
#pragma unroll 8
    for (int k = 0; k < HID; ++k) acc += w[1 + k] * hrow[k];
    float hid = fmaxf(acc, 0.f);
    __shared__ float r0[256], r1[256];
    r0[j] = hid * out_w[j];
    r1[j] = hid * out_w[HID + j];
    __syncthreads();
    for (int off = 128; off > 0; off >>= 1) {
        if (j < off) { r0[j] += r0[j + off]; r1[j] += r1[j + off]; }
        __syncthreads();
    }
    if (j == 0) {
        float l0 = r0[0] + out_b[0];
        float l1 = r1[0] + out_b[1];
        float m = fmaxf(l0, l1);
        float e0 = __expf(l0 - m), e1 = __expf(l1 - m);
        float inv = 1.0f / (e0 + e1);
        out[b * 2 + 0] = e0 * inv;
        out[b * 2 + 1] = e1 * inv;
    }
}

// ---------- launch ----------
extern "C" void kernel_launch(void* const* d_in, const int* in_sizes, int n_in,
                              void* d_out, int out_size, void* d_ws, size_t ws_size,
                              hipStream_t stream) {
    const float* x      = (const float*)d_in[0];
    const float* conv_w = (const float*)d_in[1];
    const float* conv_b = (const float*)d_in[2];
    const float* Wih    = (const float*)d_in[3];
    const float* Whh    = (const float*)d_in[4];
    const float* bih    = (const float*)d_in[5];
    const float* bhh    = (const float*)d_in[6];
    const float* fcw    = (const float*)d_in[7];
    const float* fcb    = (const float*)d_in[8];
    const float* outw   = (const float*)d_in[9];
    const float* outb   = (const float*)d_in[10];
    float* out = (float*)d_out;

    uint8_t* ws = (uint8_t*)d_ws;
    uint32_t* wreg  = (uint32_t*)ws;
    uint32_t* wtail = (uint32_t*)(ws + OFF_WTAIL);
    float* bias  = (float*)(ws + OFF_BIAS);
    float* convf = (float*)(ws + OFF_CONVF);
    float* ksim  = (float*)(ws + OFF_KSIM);
    float* h_out = (float*)(ws + OFF_HOUT);

    prep_kernel<<<512, 256, 0, stream>>>(Whh, bih, bhh, wreg, wtail, bias);
    feat_kernel<<<BATCH, 256, 0, stream>>>(x, conv_w, conv_b, convf, ksim);

    // 36864 (tail) + 128 + 128 (h dbuf) + 768 (pi/pg/po) dwords = 151552 B
    const size_t smem_bytes = (size_t)(TAIL_DW + 128 + 128 + 768) * 4;
    hipFuncSetAttribute((const void*)recur_kernel,
                        hipFuncAttributeMaxDynamicSharedMemorySize, (int)smem_bytes);
    recur_kernel<<<BATCH, 1024, smem_bytes, stream>>>(x, Wih, wreg, wtail, bias, h_out);

    head_kernel<<<BATCH, 256, 0, stream>>>(fcw, fcb, outw, outb, convf, ksim, h_out, out);
}